// Round 3
// baseline (406.000 us; speedup 1.0000x reference)
//
#include <hip/hip_runtime.h>
#include <hip/hip_bf16.h>

// GapModel: per_row[n] = (1/||ps_n||^2) * sum_m w[s_n,m] * (ps_n . sp[s_n,m])^2
// energy[t] = sum_{n: sid[n]==t} per_row[n]
//
// R3: pre-convert ps/sp to bf16 (streaming pass, norm fused) -> MFMA GEMM with
// global_load_lds width=16 staging (m97 recipe), BK=64 (32 MFMA/barrier),
// XOR chunk swizzle so fragment ds_read_b128 is 2-way (free) instead of 16-way.
// R2 kernel retained as fallback when ws_size can't hold the bf16 copy.

constexpr int kNEnv     = 100000;
constexpr int kDPS      = 512;
constexpr int kNSpecies = 4;
constexpr int kNSupport = 256;
constexpr int kCap      = 32768;

constexpr int BN = 128;
constexpr int BM = 128;

typedef __attribute__((ext_vector_type(8))) short short8;
typedef __attribute__((ext_vector_type(4))) float f32x4;

__device__ __forceinline__ short8 pack_bf16x8(const float4& a, const float4& b) {
  union { short8 v; __hip_bfloat162 h[4]; } u;
  u.h[0] = __float22bfloat162_rn({a.x, a.y});
  u.h[1] = __float22bfloat162_rn({a.z, a.w});
  u.h[2] = __float22bfloat162_rn({b.x, b.y});
  u.h[3] = __float22bfloat162_rn({b.z, b.w});
  return u.v;
}

__device__ __forceinline__ void async16(const short* g, short* l) {
  __builtin_amdgcn_global_load_lds(
      (const __attribute__((address_space(1))) void*)g,
      (__attribute__((address_space(3))) void*)l, 16, 0, 0);
}

// ---------------- single-pass species bucket scatter ----------------
__global__ void scatter_kernel(const int* __restrict__ species, const int* __restrict__ sid,
                               int* __restrict__ cnt, int* __restrict__ perm,
                               int* __restrict__ sidp) {
  __shared__ int lcnt[kNSpecies];
  __shared__ int lbase[kNSpecies];
  int t = threadIdx.x;
  if (t < kNSpecies) lcnt[t] = 0;
  __syncthreads();
  int i = blockIdx.x * 256 + t;
  bool v = i < kNEnv;
  int s = 0, r = 0, g = 0;
  if (v) { s = species[i]; r = atomicAdd(&lcnt[s], 1); g = sid[i]; }
  __syncthreads();
  if (t < kNSpecies) lbase[t] = lcnt[t] ? atomicAdd(&cnt[t], lcnt[t]) : 0;
  __syncthreads();
  if (v) {
    int d = s * kCap + lbase[s] + r;
    perm[d] = i;
    sidp[d] = g;
  }
}

// ---------------- fp32 -> bf16 conversion + row norms (streaming) ----------------
__global__ __launch_bounds__(256) void convert_kernel(
    const float* __restrict__ ps, const float* __restrict__ sp,
    short* __restrict__ a_bf, short* __restrict__ sp_bf, float* __restrict__ inv_sq) {
  const int b = blockIdx.x, wv = threadIdx.x >> 6, lane = threadIdx.x & 63;
  if (b < kNEnv / 4) {
    int row = b * 4 + wv;
    const float4* src = (const float4*)(ps + (size_t)row * kDPS) + lane * 2;
    float4 x = src[0], y = src[1];
    float s = x.x * x.x + x.y * x.y + x.z * x.z + x.w * x.w
            + y.x * y.x + y.y * y.y + y.z * y.z + y.w * y.w;
    *(short8*)(a_bf + (size_t)row * kDPS + lane * 8) = pack_bf16x8(x, y);
    #pragma unroll
    for (int off = 1; off < 64; off <<= 1) s += __shfl_xor(s, off, 64);
    if (lane == 0) inv_sq[row] = 1.0f / s;
  } else {
    int row = (b - kNEnv / 4) * 4 + wv;  // 0..1023
    const float4* src = (const float4*)(sp + (size_t)row * kDPS) + lane * 2;
    *(short8*)(sp_bf + (size_t)row * kDPS + lane * 8) = pack_bf16x8(src[0], src[1]);
  }
}

// ---------------- async-staged bf16 MFMA GEMM + epilogue ----------------
// Tile 128 env x 128 m, BK=64 (2 MFMA K-steps, 32 MFMA/wave per barrier).
// LDS rows: 64 bf16 = 128 B = 8 x 16B chunks; chunk c of row r stored at slot
// c ^ (r&7) so frag ds_read_b128 hits 2-way banks (free). global_load_lds does
// the swizzle on the gather side (per-lane global addr, forced-linear LDS).
__global__ __launch_bounds__(256) void gap_gemm_async(
    const short* __restrict__ a_bf, const short* __restrict__ sp_bf,
    const float* __restrict__ w, const int* __restrict__ cnt,
    const int* __restrict__ perm, const int* __restrict__ sidp,
    const float* __restrict__ inv_sq, float* __restrict__ energy) {
  const int s     = blockIdx.z;
  const int count = min(cnt[s], kCap);
  const int tile0 = blockIdx.x * BN;
  if (tile0 >= count) return;
  const int m0    = blockIdx.y * BM;

  __shared__ short a_sh[BN * 64];   // 16 KB, row stride 64 shorts
  __shared__ short b_sh[BM * 64];   // 16 KB
  __shared__ float red[4][64];
  __shared__ int   prm[BN];

  const int tid  = threadIdx.x;
  const int wv   = tid >> 6;
  const int lane = tid & 63;

  if (tid < BN) {
    int ge = tile0 + tid;
    prm[tid] = perm[s * kCap + (ge < count ? ge : count - 1)];
  }
  __syncthreads();

  // staging: round j (0..3), wave wv -> rows j*32+wv*8 .. +8; lane covers
  // row sub-index lane>>3, LDS chunk lane&7 which must hold global chunk
  // (lane&7)^(lane>>3)  (since r&7 == lane>>3 for 8-aligned row bases).
  const int srow   = lane >> 3;
  const int schunk = (lane & 7) ^ srow;
  const short* gA[4];
  const short* gB[4];
  #pragma unroll
  for (int j = 0; j < 4; ++j) {
    int r = j * 32 + wv * 8 + srow;
    gA[j] = a_bf + (size_t)prm[r] * kDPS + schunk * 8;
    gB[j] = sp_bf + ((size_t)(s * kNSupport + m0 + r)) * kDPS + schunk * 8;
  }

  const int wv_e = (wv & 1) * 64;
  const int wv_m = (wv >> 1) * 64;
  const int l15  = lane & 15;
  const int lq   = lane >> 4;

  const float* w_s = w + s * kNSupport;
  float wgt[4];
  #pragma unroll
  for (int fj = 0; fj < 4; ++fj) wgt[fj] = w_s[m0 + wv_m + fj * 16 + l15];

  f32x4 acc[4][4];
  #pragma unroll
  for (int i = 0; i < 4; ++i)
    #pragma unroll
    for (int j = 0; j < 4; ++j) acc[i][j] = (f32x4)0.f;

  for (int k0 = 0; k0 < kDPS; k0 += 64) {
    __syncthreads();  // previous LDS reads done
    #pragma unroll
    for (int j = 0; j < 4; ++j) {
      short* base_a = &a_sh[(j * 4 + wv) * 512];  // 512 shorts = 1 KB per wave-round
      short* base_b = &b_sh[(j * 4 + wv) * 512];
      async16(gA[j] + k0, base_a);
      async16(gB[j] + k0, base_b);
    }
    __syncthreads();  // vmcnt(0) drain before barrier -> LDS valid
    #pragma unroll
    for (int ks = 0; ks < 2; ++ks) {
      short8 af[4], bfr[4];
      #pragma unroll
      for (int f = 0; f < 4; ++f) {
        int rowA = wv_e + f * 16 + l15;
        af[f]  = *(const short8*)&a_sh[rowA * 64 + (((ks * 4 + lq) ^ (rowA & 7)) * 8)];
        int rowB = wv_m + f * 16 + l15;
        bfr[f] = *(const short8*)&b_sh[rowB * 64 + (((ks * 4 + lq) ^ (rowB & 7)) * 8)];
      }
      #pragma unroll
      for (int fi = 0; fi < 4; ++fi)
        #pragma unroll
        for (int fj = 0; fj < 4; ++fj)
          acc[fi][fj] = __builtin_amdgcn_mfma_f32_16x16x32_bf16(af[fi], bfr[fj], acc[fi][fj], 0, 0, 0);
    }
  }

  // epilogue: contrib = sum_m w_m * C^2 ; C/D: col(m)=lane&15, row(env)=lq*4+reg
  #pragma unroll
  for (int fi = 0; fi < 4; ++fi) {
    #pragma unroll
    for (int r = 0; r < 4; ++r) {
      float p = 0.f;
      #pragma unroll
      for (int fj = 0; fj < 4; ++fj) {
        float c = acc[fi][fj][r];
        p += c * c * wgt[fj];
      }
      p += __shfl_xor(p, 1, 64);
      p += __shfl_xor(p, 2, 64);
      p += __shfl_xor(p, 4, 64);
      p += __shfl_xor(p, 8, 64);
      if (l15 == 0) red[wv][fi * 16 + lq * 4 + r] = p;
    }
  }
  __syncthreads();
  if (tid < BN) {
    int h = tid >> 6, el = tid & 63;
    int row = h * 64 + el;
    float v = red[h][el] + red[h + 2][el];
    int g = tile0 + row;
    if (g < count) {
      int env = prm[row];
      atomicAdd(&energy[sidp[s * kCap + g]], v * inv_sq[env]);
    }
  }
}

// ---------------- R2 fallback (fp32 staging, in-loop convert) ----------------
constexpr int LDSS = 40;
__global__ __launch_bounds__(256) void gap_gemm_r2(
    const float* __restrict__ ps, const float* __restrict__ sp,
    const float* __restrict__ w, const int* __restrict__ cnt,
    const int* __restrict__ perm, const int* __restrict__ sidp,
    float* __restrict__ energy) {
  const int s     = blockIdx.z;
  const int count = min(cnt[s], kCap);
  const int tile0 = blockIdx.x * BN;
  if (tile0 >= count) return;
  const int m0    = blockIdx.y * BM;

  __shared__ short a_sh[BN * LDSS];
  __shared__ short b_sh[BM * LDSS];
  __shared__ float red[4][64];
  __shared__ float sqs[2][BN];

  const int tid  = threadIdx.x;
  const int wv   = tid >> 6;
  const int lane = tid & 63;
  const int st_r = tid & 127;
  const int st_p = tid >> 7;

  const int ge   = tile0 + st_r;
  const int arow = perm[s * kCap + (ge < count ? ge : count - 1)];
  const float* a_src = ps + (size_t)arow * kDPS + st_p * 16;
  const float* b_src = sp + ((size_t)s * kNSupport + m0 + st_r) * kDPS + st_p * 16;
  const float* w_s   = w + s * kNSupport;

  const int wv_e = (wv & 1) * 64;
  const int wv_m = (wv >> 1) * 64;
  const int l15  = lane & 15;
  const int lq   = lane >> 4;

  float wgt[4];
  #pragma unroll
  for (int fj = 0; fj < 4; ++fj) wgt[fj] = w_s[m0 + wv_m + fj * 16 + l15];

  f32x4 acc[4][4];
  #pragma unroll
  for (int i = 0; i < 4; ++i)
    #pragma unroll
    for (int j = 0; j < 4; ++j) acc[i][j] = (f32x4)0.f;

  float sqsum = 0.f;
  float4 va[4], vb[4];
  #pragma unroll
  for (int j = 0; j < 4; ++j) {
    va[j] = *(const float4*)(a_src + j * 4);
    vb[j] = *(const float4*)(b_src + j * 4);
  }

  for (int k0 = 0; k0 < kDPS; k0 += 32) {
    __syncthreads();
    #pragma unroll
    for (int j = 0; j < 4; ++j)
      sqsum += va[j].x * va[j].x + va[j].y * va[j].y + va[j].z * va[j].z + va[j].w * va[j].w;
    {
      short* ap = &a_sh[st_r * LDSS + st_p * 16];
      *(short8*)(ap)     = pack_bf16x8(va[0], va[1]);
      *(short8*)(ap + 8) = pack_bf16x8(va[2], va[3]);
      short* bp = &b_sh[st_r * LDSS + st_p * 16];
      *(short8*)(bp)     = pack_bf16x8(vb[0], vb[1]);
      *(short8*)(bp + 8) = pack_bf16x8(vb[2], vb[3]);
    }
    __syncthreads();
    if (k0 + 32 < kDPS) {
      #pragma unroll
      for (int j = 0; j < 4; ++j) {
        va[j] = *(const float4*)(a_src + k0 + 32 + j * 4);
        vb[j] = *(const float4*)(b_src + k0 + 32 + j * 4);
      }
    }
    short8 af[4], bfr[4];
    #pragma unroll
    for (int fi = 0; fi < 4; ++fi)
      af[fi] = *(const short8*)&a_sh[(wv_e + fi * 16 + l15) * LDSS + lq * 8];
    #pragma unroll
    for (int fj = 0; fj < 4; ++fj)
      bfr[fj] = *(const short8*)&b_sh[(wv_m + fj * 16 + l15) * LDSS + lq * 8];
    #pragma unroll
    for (int fi = 0; fi < 4; ++fi)
      #pragma unroll
      for (int fj = 0; fj < 4; ++fj)
        acc[fi][fj] = __builtin_amdgcn_mfma_f32_16x16x32_bf16(af[fi], bfr[fj], acc[fi][fj], 0, 0, 0);
  }

  sqs[st_p][st_r] = sqsum;
  #pragma unroll
  for (int fi = 0; fi < 4; ++fi) {
    #pragma unroll
    for (int r = 0; r < 4; ++r) {
      float p = 0.f;
      #pragma unroll
      for (int fj = 0; fj < 4; ++fj) {
        float c = acc[fi][fj][r];
        p += c * c * wgt[fj];
      }
      p += __shfl_xor(p, 1, 64);
      p += __shfl_xor(p, 2, 64);
      p += __shfl_xor(p, 4, 64);
      p += __shfl_xor(p, 8, 64);
      if (l15 == 0) red[wv][fi * 16 + lq * 4 + r] = p;
    }
  }
  __syncthreads();
  if (tid < BN) {
    int h = tid >> 6, el = tid & 63;
    int row = h * 64 + el;
    float v = red[h][el] + red[h + 2][el];
    int g = tile0 + row;
    if (g < count) {
      float inv = 1.0f / (sqs[0][row] + sqs[1][row]);
      atomicAdd(&energy[sidp[s * kCap + g]], v * inv);
    }
  }
}

extern "C" void kernel_launch(void* const* d_in, const int* in_sizes, int n_in,
                              void* d_out, int out_size, void* d_ws, size_t ws_size,
                              hipStream_t stream) {
  const float* ps      = (const float*)d_in[0];
  const float* sp      = (const float*)d_in[1];
  const float* w       = (const float*)d_in[2];
  const int*   species = (const int*)d_in[3];
  const int*   sid     = (const int*)d_in[4];
  float* energy = (float*)d_out;

  char* wsb = (char*)d_ws;
  size_t off = 0;
  int* cnt  = (int*)(wsb + off); off += 256;
  int* perm = (int*)(wsb + off); off += (size_t)kNSpecies * kCap * 4;
  int* sidp = (int*)(wsb + off); off += (size_t)kNSpecies * kCap * 4;
  float* inv_sq = (float*)(wsb + off); off += (size_t)kNEnv * 4; off = (off + 255) & ~255ull;
  short* sp_bf  = (short*)(wsb + off); off += (size_t)kNSpecies * kNSupport * kDPS * 2; off = (off + 255) & ~255ull;
  short* a_bf   = (short*)(wsb + off);
  size_t need = off + (size_t)kNEnv * kDPS * 2;

  hipMemsetAsync(cnt, 0, 16, stream);
  hipMemsetAsync(energy, 0, out_size * sizeof(float), stream);

  scatter_kernel<<<(kNEnv + 255) / 256, 256, 0, stream>>>(species, sid, cnt, perm, sidp);

  dim3 grid(kCap / BN, kNSupport / BM, kNSpecies);
  if (ws_size >= need) {
    convert_kernel<<<kNEnv / 4 + (kNSpecies * kNSupport) / 4, 256, 0, stream>>>(
        ps, sp, a_bf, sp_bf, inv_sq);
    gap_gemm_async<<<grid, 256, 0, stream>>>(a_bf, sp_bf, w, cnt, perm, sidp, inv_sq, energy);
  } else {
    gap_gemm_r2<<<grid, 256, 0, stream>>>(ps, sp, w, cnt, perm, sidp, energy);
  }
}